// Round 6
// baseline (9156.467 us; speedup 1.0000x reference)
//
#include <hip/hip_runtime.h>
#include <math.h>

#define HD 1024
#define SEQ 512
#define VOCAB 32000
#define NCHUNK 8000
#define SCAN_WGS 256   // per chain; 3 chains fused = 768 WGs (3 waves/CU)
#define SENT 0xAAAAAAAAu

// ---------------- init: LSE state ----------------
__global__ __launch_bounds__(512) void init_state(float* m, float* s, float* tl) {
    int tid = threadIdx.x;
    m[tid] = -INFINITY;
    s[tid] = 0.f;
    tl[tid] = 0.f;
}

// ---------------- sentinel fill for scan output buffers ----------------
__global__ __launch_bounds__(256) void fill_sentinel(float4* p, int n4) {
    const float s = __uint_as_float(SENT);
    const float4 v = {s, s, s, s};
    int i = blockIdx.x * 256 + threadIdx.x;
    int stride = gridDim.x * 256;
    for (; i < n4; i += stride) p[i] = v;
}

// ---------------- embedding gather: out[t][:] = emb[idx[t]][:] ----------------
__global__ __launch_bounds__(256) void gather_rows(const float* __restrict__ emb,
                                                   const int* __restrict__ idx,
                                                   float* __restrict__ out, int ncols) {
    int t = blockIdx.x;
    int src = idx[t];
    const float4* sp = (const float4*)(emb + (size_t)src * ncols);
    float4* dp = (float4*)(out + (size_t)t * ncols);
    for (int i = threadIdx.x; i < ncols / 4; i += blockDim.x) dp[i] = sp[i];
}

// ---------------- copy Hp into right half of CH ----------------
__global__ __launch_bounds__(256) void copy_right(const float* __restrict__ Hp, float* __restrict__ CH) {
    int t = blockIdx.x;
    const float4* sp = (const float4*)(Hp + (size_t)t * HD);
    float4* dp = (float4*)(CH + (size_t)t * (2 * HD) + HD);
    for (int i = threadIdx.x; i < HD / 4; i += blockDim.x) dp[i] = sp[i];
}

// ---------------- transpose: in[R][C] -> out[C][R] ----------------
__global__ __launch_bounds__(256) void transpose_k(const float* __restrict__ in, float* __restrict__ out,
                                                   int R, int C) {
    __shared__ float tile[32][33];
    int c0 = blockIdx.x * 32, r0 = blockIdx.y * 32;
    int tx = threadIdx.x, ty = threadIdx.y;  // block (32,8)
    for (int i = ty; i < 32; i += 8)
        tile[i][tx] = in[(size_t)(r0 + i) * C + c0 + tx];
    __syncthreads();
    for (int i = ty; i < 32; i += 8)
        out[(size_t)(c0 + i) * R + r0 + tx] = tile[tx][i];
}

// ---------------- fp32 GEMM: C[M,N] = act(A[M,K] @ B[N,K]^T + bias[N]) ----------------
__global__ __launch_bounds__(256) void gemm_nt(const float* __restrict__ A, const float* __restrict__ B,
                                               const float* __restrict__ bias, float* __restrict__ C,
                                               int M, int N, int K, int ldc, int act) {
    __shared__ float As[16][68];
    __shared__ float Bs[16][68];
    const int tid = threadIdx.x;
    const int row0 = blockIdx.y * 64, col0 = blockIdx.x * 64;
    const int tx = tid & 15, ty = tid >> 4;
    const int lr = tid >> 2, lk = (tid & 3) << 2;
    const float* Ap = A + (size_t)(row0 + lr) * K + lk;
    const float* Bp = B + (size_t)(col0 + lr) * K + lk;
    float acc[4][4] = {};
    for (int k0 = 0; k0 < K; k0 += 16) {
        float4 a = *(const float4*)(Ap + k0);
        float4 b = *(const float4*)(Bp + k0);
        As[lk + 0][lr] = a.x; As[lk + 1][lr] = a.y; As[lk + 2][lr] = a.z; As[lk + 3][lr] = a.w;
        Bs[lk + 0][lr] = b.x; Bs[lk + 1][lr] = b.y; Bs[lk + 2][lr] = b.z; Bs[lk + 3][lr] = b.w;
        __syncthreads();
#pragma unroll
        for (int kk = 0; kk < 16; ++kk) {
            const float4 av = *(const float4*)&As[kk][ty * 4];
            const float4 bv = *(const float4*)&Bs[kk][tx * 4];
            const float a0[4] = {av.x, av.y, av.z, av.w};
            const float b0[4] = {bv.x, bv.y, bv.z, bv.w};
#pragma unroll
            for (int i = 0; i < 4; ++i)
#pragma unroll
                for (int j = 0; j < 4; ++j) acc[i][j] += a0[i] * b0[j];
        }
        __syncthreads();
    }
#pragma unroll
    for (int i = 0; i < 4; ++i) {
        float4 v;
        float* vp = &v.x;
#pragma unroll
        for (int j = 0; j < 4; ++j) {
            float x = acc[i][j];
            if (bias) x += bias[col0 + tx * 4 + j];
            if (act) x = tanhf(x);
            vp[j] = x;
        }
        *(float4*)(C + (size_t)(row0 + ty * 4 + i) * ldc + col0 + tx * 4) = v;
    }
}

// ---------------- shared scan body: h_t = tanh(X[t] + Wh @ h_{t-1}) ----------------
// Data-carried sentinel sync over RELAXED agent-scope atomics (no acquire/release
// cache maintenance).  WG wid owns rows [4wid,4wid+4); lane l holds 16 cols/row.
__device__ __forceinline__ void scan_simple(const float* __restrict__ X,
                                            const float* __restrict__ Wh,
                                            const float* __restrict__ h0,
                                            float* __restrict__ Hout,
                                            int T, int write_h0,
                                            int wid, int lane) {
    const int row0 = wid * 4;
    float4 w[4][4];
#pragma unroll
    for (int r = 0; r < 4; ++r) {
        const float* wp = Wh + (size_t)(row0 + r) * HD + lane * 16;
#pragma unroll
        for (int c = 0; c < 4; ++c) w[r][c] = *(const float4*)(wp + c * 4);
    }
    const int out0 = write_h0 ? 1 : 0;
    if (write_h0 && lane < 4) Hout[row0 + lane] = h0[row0 + lane];
    float h[16];
#pragma unroll
    for (int c = 0; c < 16; ++c) h[c] = h0[lane * 16 + c];

    for (int t = 0; t < T; ++t) {
        float xv = 0.f;
        if (lane < 4) xv = X[(size_t)t * HD + row0 + lane];
        float acc[4];
#pragma unroll
        for (int r = 0; r < 4; ++r) {
            float a = 0.f;
#pragma unroll
            for (int c = 0; c < 4; ++c) {
                const float4 wv = w[r][c];
                a += wv.x * h[c * 4 + 0] + wv.y * h[c * 4 + 1] +
                     wv.z * h[c * 4 + 2] + wv.w * h[c * 4 + 3];
            }
            acc[r] = a;
        }
#pragma unroll
        for (int r = 0; r < 4; ++r) {
#pragma unroll
            for (int off = 32; off; off >>= 1) acc[r] += __shfl_xor(acc[r], off);
        }
        float* orow = Hout + (size_t)(out0 + t) * HD + row0;
        if (lane < 4) {
            float v = tanhf(xv + acc[lane]);
            __hip_atomic_store(&orow[lane], v, __ATOMIC_RELAXED, __HIP_MEMORY_SCOPE_AGENT);
        }
        if (t + 1 < T) {
            const float* hrow = Hout + (size_t)(out0 + t) * HD + lane * 16;
            int ok;
            do {
                unsigned bad = 0;
#pragma unroll
                for (int c = 0; c < 16; ++c) {
                    h[c] = __hip_atomic_load(&hrow[c], __ATOMIC_RELAXED, __HIP_MEMORY_SCOPE_AGENT);
                    bad |= (unsigned)(__float_as_uint(h[c]) == SENT);
                }
                ok = (bad == 0);
            } while (!__all(ok));
        }
    }
}

// ---------------- fused 3-chain scan ----------------
// grid = 768 WGs x 64 threads, 3 waves/CU, all resident.
//   grp 0 (wid 0..255):   enc layer 1:  H1[t]  = tanh(Xa[t] + Wh1 @ H1[t-1])
//   grp 1 (wid 256..511): enc layer 2:  Henc[t]= tanh(b2 + Wx2 @ H1[t] + Wh2 @ Henc[t-1])
//                         (polls H1[t] from grp 0 — pipeline lag is automatic)
//   grp 2 (wid 512..767): decoder:      Hp[t]  = tanh(Xc[t-1] + dWh @ Hp[t-1]), Hp[0]=dh0
// Chains A and C are independent; B lags A by ~1 step.  Effective sync-chain
// length ~513 steps instead of 3x512 back-to-back.
__global__ __launch_bounds__(64) void scan_all(const float* __restrict__ Xa,
                                               const float* __restrict__ Wh1,
                                               const float* __restrict__ h01,
                                               float* __restrict__ H1,
                                               const float* __restrict__ Wx2,
                                               const float* __restrict__ Wh2,
                                               const float* __restrict__ b2,
                                               const float* __restrict__ h02,
                                               float* __restrict__ Henc,
                                               const float* __restrict__ Xc,
                                               const float* __restrict__ dWh,
                                               const float* __restrict__ dh0,
                                               float* __restrict__ Hp) {
    const int grp = blockIdx.x >> 8;
    const int wid = blockIdx.x & 255;
    const int lane = threadIdx.x;
    if (grp == 0) {
        scan_simple(Xa, Wh1, h01, H1, SEQ, 0, wid, lane);
    } else if (grp == 2) {
        scan_simple(Xc, dWh, dh0, Hp, SEQ - 1, 1, wid, lane);
    } else {
        // ---- chain B: two matvecs per step, weights Wx2 & Wh2 in VGPRs ----
        const int row0 = wid * 4;
        float4 wx[4][4], wh[4][4];
#pragma unroll
        for (int r = 0; r < 4; ++r) {
            const float* xp = Wx2 + (size_t)(row0 + r) * HD + lane * 16;
            const float* hp = Wh2 + (size_t)(row0 + r) * HD + lane * 16;
#pragma unroll
            for (int c = 0; c < 4; ++c) {
                wx[r][c] = *(const float4*)(xp + c * 4);
                wh[r][c] = *(const float4*)(hp + c * 4);
            }
        }
        float bias = (lane < 4) ? b2[row0 + lane] : 0.f;
        float hh[16];
#pragma unroll
        for (int c = 0; c < 16; ++c) hh[c] = h02[lane * 16 + c];
        // ---- pre-loop: poll H1[0] ----
        float hx[16];
        {
            const float* xrow = H1 + lane * 16;
            int ok;
            do {
                unsigned bad = 0;
#pragma unroll
                for (int c = 0; c < 16; ++c) {
                    hx[c] = __hip_atomic_load(&xrow[c], __ATOMIC_RELAXED, __HIP_MEMORY_SCOPE_AGENT);
                    bad |= (unsigned)(__float_as_uint(hx[c]) == SENT);
                }
                ok = (bad == 0);
            } while (!__all(ok));
        }
        for (int t = 0; t < SEQ; ++t) {
            float acc[4];
#pragma unroll
            for (int r = 0; r < 4; ++r) {
                float a = 0.f;
#pragma unroll
                for (int c = 0; c < 4; ++c) {
                    const float4 xw = wx[r][c];
                    const float4 hw = wh[r][c];
                    a += xw.x * hx[c * 4 + 0] + xw.y * hx[c * 4 + 1] +
                         xw.z * hx[c * 4 + 2] + xw.w * hx[c * 4 + 3];
                    a += hw.x * hh[c * 4 + 0] + hw.y * hh[c * 4 + 1] +
                         hw.z * hh[c * 4 + 2] + hw.w * hh[c * 4 + 3];
                }
                acc[r] = a;
            }
#pragma unroll
            for (int r = 0; r < 4; ++r) {
#pragma unroll
                for (int off = 32; off; off >>= 1) acc[r] += __shfl_xor(acc[r], off);
            }
            float* orow = Henc + (size_t)t * HD + row0;
            if (lane < 4) {
                float v = tanhf(bias + acc[lane]);
                __hip_atomic_store(&orow[lane], v, __ATOMIC_RELAXED, __HIP_MEMORY_SCOPE_AGENT);
            }
            if (t + 1 < SEQ) {
                // ---- merged poll: Henc[t] -> hh  AND  H1[t+1] -> hx ----
                const float* hrow = Henc + (size_t)t * HD + lane * 16;
                const float* xrow = H1 + (size_t)(t + 1) * HD + lane * 16;
                int ok;
                do {
                    unsigned bad = 0;
#pragma unroll
                    for (int c = 0; c < 16; ++c) {
                        hh[c] = __hip_atomic_load(&hrow[c], __ATOMIC_RELAXED, __HIP_MEMORY_SCOPE_AGENT);
                        bad |= (unsigned)(__float_as_uint(hh[c]) == SENT);
                        hx[c] = __hip_atomic_load(&xrow[c], __ATOMIC_RELAXED, __HIP_MEMORY_SCOPE_AGENT);
                        bad |= (unsigned)(__float_as_uint(hx[c]) == SENT);
                    }
                    ok = (bad == 0);
                } while (!__all(ok));
            }
        }
    }
}

// ---------------- row softmax in place ----------------
__global__ __launch_bounds__(256) void softmax_rows(float* __restrict__ S, int N) {
    __shared__ float red[256];
    const int row = blockIdx.x, tid = threadIdx.x;
    float* r = S + (size_t)row * N;
    float lm = -INFINITY;
    for (int i = tid; i < N; i += 256) lm = fmaxf(lm, r[i]);
    red[tid] = lm; __syncthreads();
    for (int o = 128; o; o >>= 1) { if (tid < o) red[tid] = fmaxf(red[tid], red[tid + o]); __syncthreads(); }
    const float M = red[0]; __syncthreads();
    float ls = 0.f;
    for (int i = tid; i < N; i += 256) { float e = expf(r[i] - M); r[i] = e; ls += e; }
    red[tid] = ls; __syncthreads();
    for (int o = 128; o; o >>= 1) { if (tid < o) red[tid] += red[tid + o]; __syncthreads(); }
    const float inv = 1.f / red[0];
    for (int i = tid; i < N; i += 256) r[i] *= inv;
}

// ---------------- online logsumexp over a logits chunk ----------------
__global__ __launch_bounds__(256) void lse_chunk(const float* __restrict__ L, int CN, int c0,
                                                 const int* __restrict__ tgt, float* __restrict__ m,
                                                 float* __restrict__ s, float* __restrict__ tl) {
    __shared__ float red[256];
    const int row = blockIdx.x, tid = threadIdx.x;
    const float* lr = L + (size_t)row * CN;
    float lm = -INFINITY;
    for (int i = tid; i < CN; i += 256) lm = fmaxf(lm, lr[i]);
    red[tid] = lm; __syncthreads();
    for (int o = 128; o; o >>= 1) { if (tid < o) red[tid] = fmaxf(red[tid], red[tid + o]); __syncthreads(); }
    const float M = red[0]; __syncthreads();
    float ls = 0.f;
    for (int i = tid; i < CN; i += 256) ls += expf(lr[i] - M);
    red[tid] = ls; __syncthreads();
    for (int o = 128; o; o >>= 1) { if (tid < o) red[tid] += red[tid + o]; __syncthreads(); }
    if (tid == 0) {
        const float S = red[0];
        const float m0 = m[row];
        const float nm = fmaxf(m0, M);
        const float s0 = s[row];
        const float ns = (m0 == -INFINITY ? 0.f : s0 * expf(m0 - nm)) + S * expf(M - nm);
        m[row] = nm; s[row] = ns;
        const int tg = tgt[row] - c0;
        if (tg >= 0 && tg < CN) tl[row] = lr[tg];
    }
}

// ---------------- final: sum_t (m + log s - tgt_logit) ----------------
__global__ __launch_bounds__(512) void final_loss(const float* __restrict__ m, const float* __restrict__ s,
                                                  const float* __restrict__ tl, float* __restrict__ out) {
    __shared__ float red[512];
    const int tid = threadIdx.x;
    red[tid] = m[tid] + logf(s[tid]) - tl[tid];
    __syncthreads();
    for (int o = 256; o; o >>= 1) { if (tid < o) red[tid] += red[tid + o]; __syncthreads(); }
    if (tid == 0) out[0] = red[0];
}

extern "C" void kernel_launch(void* const* d_in, const int* in_sizes, int n_in,
                              void* d_out, int out_size, void* d_ws, size_t ws_size,
                              hipStream_t stream) {
    const int* src_nums  = (const int*)d_in[0];
    const int* tgt_nums  = (const int*)d_in[1];
    const float* src_emb = (const float*)d_in[2];
    const float* Wx1     = (const float*)d_in[3];
    const float* Wh1     = (const float*)d_in[4];
    const float* b1      = (const float*)d_in[5];
    const float* h01     = (const float*)d_in[6];
    const float* Wx2     = (const float*)d_in[7];
    const float* Wh2     = (const float*)d_in[8];
    const float* b2      = (const float*)d_in[9];
    const float* h02     = (const float*)d_in[10];
    const float* tgt_emb = (const float*)d_in[11];
    const float* dh0     = (const float*)d_in[12];
    const float* dWx     = (const float*)d_in[13];
    const float* dWh     = (const float*)d_in[14];
    const float* db      = (const float*)d_in[15];
    const float* tnhW    = (const float*)d_in[16];
    const float* tnhb    = (const float*)d_in[17];
    const float* outW    = (const float*)d_in[18];
    const float* outb    = (const float*)d_in[19];
    float* out = (float*)d_out;

    float* ws = (float*)d_ws;
    size_t off = 0;
    auto alloc = [&](size_t n) { float* p = ws + off; off += n; return p; };
    float* E     = alloc((size_t)SEQ * HD);
    float* Xa    = alloc((size_t)SEQ * HD);
    float* Xc    = alloc((size_t)SEQ * HD);
    float* H1    = alloc((size_t)SEQ * HD);   // H1, Henc, Hp contiguous: one sentinel fill
    float* Henc  = alloc((size_t)SEQ * HD);
    float* Hp    = alloc((size_t)SEQ * HD);
    float* HencT = alloc((size_t)HD * SEQ);
    float* Satt  = alloc((size_t)SEQ * SEQ);
    float* CH    = alloc((size_t)SEQ * 2 * HD);
    float* Z     = alloc((size_t)SEQ * HD);
    float* Lc    = alloc((size_t)SEQ * NCHUNK);
    float* mrow  = alloc(SEQ);
    float* srow  = alloc(SEQ);
    float* tlrow = alloc(SEQ);

    init_state<<<1, 512, 0, stream>>>(mrow, srow, tlrow);
    fill_sentinel<<<768, 256, 0, stream>>>((float4*)H1, 3 * SEQ * HD / 4);

    // ---- precompute scan inputs (E reused sequentially; stream-ordered) ----
    gather_rows<<<SEQ, 256, 0, stream>>>(src_emb, src_nums, E, HD);
    gemm_nt<<<dim3(HD / 64, SEQ / 64), 256, 0, stream>>>(E, Wx1, b1, Xa, SEQ, HD, HD, HD, 0);
    gather_rows<<<SEQ, 256, 0, stream>>>(tgt_emb, tgt_nums, E, HD);
    gemm_nt<<<dim3(HD / 64, SEQ / 64), 256, 0, stream>>>(E, dWx, db, Xc, SEQ, HD, HD, HD, 0);

    // ---- all three recurrence chains, concurrent + pipelined ----
    scan_all<<<3 * SCAN_WGS, 64, 0, stream>>>(Xa, Wh1, h01, H1,
                                              Wx2, Wh2, b2, h02, Henc,
                                              Xc, dWh, dh0, Hp);

    // ---- batched attention ----
    gemm_nt<<<dim3(SEQ / 64, SEQ / 64), 256, 0, stream>>>(Hp, Henc, nullptr, Satt, SEQ, SEQ, HD, SEQ, 0);
    softmax_rows<<<SEQ, 256, 0, stream>>>(Satt, SEQ);
    transpose_k<<<dim3(HD / 32, SEQ / 32), dim3(32, 8), 0, stream>>>(Henc, HencT, SEQ, HD);
    gemm_nt<<<dim3(HD / 64, SEQ / 64), 256, 0, stream>>>(Satt, HencT, nullptr, CH, SEQ, HD, SEQ, 2 * HD, 0);
    copy_right<<<SEQ, 256, 0, stream>>>(Hp, CH);
    gemm_nt<<<dim3(HD / 64, SEQ / 64), 256, 0, stream>>>(CH, tnhW, tnhb, Z, SEQ, HD, 2 * HD, HD, 1);

    // ---- logits + online logsumexp, chunked over vocab ----
    for (int c = 0; c < VOCAB / NCHUNK; ++c) {
        gemm_nt<<<dim3(NCHUNK / 64, SEQ / 64), 256, 0, stream>>>(
            Z, outW + (size_t)c * NCHUNK * HD, outb + (size_t)c * NCHUNK, Lc, SEQ, NCHUNK, HD, NCHUNK, 0);
        lse_chunk<<<SEQ, 256, 0, stream>>>(Lc, NCHUNK, c * NCHUNK, tgt_nums, mrow, srow, tlrow);
    }
    final_loss<<<1, 512, 0, stream>>>(mrow, srow, tlrow, out);
}

// Round 7
// 5110.487 us; speedup vs baseline: 1.7917x; 1.7917x over previous
//
#include <hip/hip_runtime.h>
#include <math.h>

#define HD 1024
#define SEQ 512
#define VOCAB 32000
#define NCHUNK 8000
#define SCAN_WGS 256   // per group; 4 groups fused = 1024 WGs (1 wave each)
#define SENT 0xAAAAAAAAu

// ---------------- init: LSE state ----------------
__global__ __launch_bounds__(512) void init_state(float* m, float* s, float* tl) {
    int tid = threadIdx.x;
    m[tid] = -INFINITY;
    s[tid] = 0.f;
    tl[tid] = 0.f;
}

// ---------------- sentinel fill for scan output buffers ----------------
__global__ __launch_bounds__(256) void fill_sentinel(float4* p, int n4) {
    const float s = __uint_as_float(SENT);
    const float4 v = {s, s, s, s};
    int i = blockIdx.x * 256 + threadIdx.x;
    int stride = gridDim.x * 256;
    for (; i < n4; i += stride) p[i] = v;
}

// ---------------- embedding gather: out[t][:] = emb[idx[t]][:] ----------------
__global__ __launch_bounds__(256) void gather_rows(const float* __restrict__ emb,
                                                   const int* __restrict__ idx,
                                                   float* __restrict__ out, int ncols) {
    int t = blockIdx.x;
    int src = idx[t];
    const float4* sp = (const float4*)(emb + (size_t)src * ncols);
    float4* dp = (float4*)(out + (size_t)t * ncols);
    for (int i = threadIdx.x; i < ncols / 4; i += blockDim.x) dp[i] = sp[i];
}

// ---------------- copy Hp into right half of CH ----------------
__global__ __launch_bounds__(256) void copy_right(const float* __restrict__ Hp, float* __restrict__ CH) {
    int t = blockIdx.x;
    const float4* sp = (const float4*)(Hp + (size_t)t * HD);
    float4* dp = (float4*)(CH + (size_t)t * (2 * HD) + HD);
    for (int i = threadIdx.x; i < HD / 4; i += blockDim.x) dp[i] = sp[i];
}

// ---------------- transpose: in[R][C] -> out[C][R] ----------------
__global__ __launch_bounds__(256) void transpose_k(const float* __restrict__ in, float* __restrict__ out,
                                                   int R, int C) {
    __shared__ float tile[32][33];
    int c0 = blockIdx.x * 32, r0 = blockIdx.y * 32;
    int tx = threadIdx.x, ty = threadIdx.y;  // block (32,8)
    for (int i = ty; i < 32; i += 8)
        tile[i][tx] = in[(size_t)(r0 + i) * C + c0 + tx];
    __syncthreads();
    for (int i = ty; i < 32; i += 8)
        out[(size_t)(c0 + i) * R + r0 + tx] = tile[tx][i];
}

// ---------------- fp32 GEMM: C[M,N] = act(A[M,K] @ B[N,K]^T + bias[N]) ----------------
__global__ __launch_bounds__(256) void gemm_nt(const float* __restrict__ A, const float* __restrict__ B,
                                               const float* __restrict__ bias, float* __restrict__ C,
                                               int M, int N, int K, int ldc, int act) {
    __shared__ float As[16][68];
    __shared__ float Bs[16][68];
    const int tid = threadIdx.x;
    const int row0 = blockIdx.y * 64, col0 = blockIdx.x * 64;
    const int tx = tid & 15, ty = tid >> 4;
    const int lr = tid >> 2, lk = (tid & 3) << 2;
    const float* Ap = A + (size_t)(row0 + lr) * K + lk;
    const float* Bp = B + (size_t)(col0 + lr) * K + lk;
    float acc[4][4] = {};
    for (int k0 = 0; k0 < K; k0 += 16) {
        float4 a = *(const float4*)(Ap + k0);
        float4 b = *(const float4*)(Bp + k0);
        As[lk + 0][lr] = a.x; As[lk + 1][lr] = a.y; As[lk + 2][lr] = a.z; As[lk + 3][lr] = a.w;
        Bs[lk + 0][lr] = b.x; Bs[lk + 1][lr] = b.y; Bs[lk + 2][lr] = b.z; Bs[lk + 3][lr] = b.w;
        __syncthreads();
#pragma unroll
        for (int kk = 0; kk < 16; ++kk) {
            const float4 av = *(const float4*)&As[kk][ty * 4];
            const float4 bv = *(const float4*)&Bs[kk][tx * 4];
            const float a0[4] = {av.x, av.y, av.z, av.w};
            const float b0[4] = {bv.x, bv.y, bv.z, bv.w};
#pragma unroll
            for (int i = 0; i < 4; ++i)
#pragma unroll
                for (int j = 0; j < 4; ++j) acc[i][j] += a0[i] * b0[j];
        }
        __syncthreads();
    }
#pragma unroll
    for (int i = 0; i < 4; ++i) {
        float4 v;
        float* vp = &v.x;
#pragma unroll
        for (int j = 0; j < 4; ++j) {
            float x = acc[i][j];
            if (bias) x += bias[col0 + tx * 4 + j];
            if (act) x = tanhf(x);
            vp[j] = x;
        }
        *(float4*)(C + (size_t)(row0 + ty * 4 + i) * ldc + col0 + tx * 4) = v;
    }
}

// ---- pending-mask poll of one 16-dword slice: re-reads only still-sentinel dwords ----
__device__ __forceinline__ void poll_row16(const float* __restrict__ row, float* h) {
    unsigned pend = 0xFFFFu;
    for (;;) {
#pragma unroll
        for (int c = 0; c < 16; ++c) {
            if (pend & (1u << c)) {
                float v = __hip_atomic_load(&row[c], __ATOMIC_RELAXED, __HIP_MEMORY_SCOPE_AGENT);
                h[c] = v;
                if (__float_as_uint(v) != SENT) pend &= ~(1u << c);
            }
        }
        if (__all(pend == 0)) break;
        __builtin_amdgcn_s_sleep(1);
    }
}

// ---------------- scan body: h_t = tanh(X[t] + Wh @ h_{t-1}) ----------------
// Data-carried sentinel sync over RELAXED agent-scope atomics.  WG wid owns rows
// [4wid,4wid+4); lane l holds Wh[row][16l..16l+16) in VGPRs (64 VGPRs).
__device__ __forceinline__ void scan_simple(const float* __restrict__ X,
                                            const float* __restrict__ Wh,
                                            const float* __restrict__ h0,
                                            float* __restrict__ Hout,
                                            int T, int write_h0,
                                            int wid, int lane) {
    const int row0 = wid * 4;
    float4 w[4][4];
#pragma unroll
    for (int r = 0; r < 4; ++r) {
        const float* wp = Wh + (size_t)(row0 + r) * HD + lane * 16;
#pragma unroll
        for (int c = 0; c < 4; ++c) w[r][c] = *(const float4*)(wp + c * 4);
    }
    const int out0 = write_h0 ? 1 : 0;
    if (write_h0 && lane < 4) Hout[row0 + lane] = h0[row0 + lane];
    float h[16];
#pragma unroll
    for (int c = 0; c < 16; ++c) h[c] = h0[lane * 16 + c];

    for (int t = 0; t < T; ++t) {
        float xv = 0.f;
        if (lane < 4) xv = X[(size_t)t * HD + row0 + lane];
        float acc[4];
#pragma unroll
        for (int r = 0; r < 4; ++r) {
            float a = 0.f;
#pragma unroll
            for (int c = 0; c < 4; ++c) {
                const float4 wv = w[r][c];
                a += wv.x * h[c * 4 + 0] + wv.y * h[c * 4 + 1] +
                     wv.z * h[c * 4 + 2] + wv.w * h[c * 4 + 3];
            }
            acc[r] = a;
        }
#pragma unroll
        for (int r = 0; r < 4; ++r) {
#pragma unroll
            for (int off = 32; off; off >>= 1) acc[r] += __shfl_xor(acc[r], off);
        }
        float* orow = Hout + (size_t)(out0 + t) * HD + row0;
        if (lane < 4) {
            float v = tanhf(xv + acc[lane]);
            __hip_atomic_store(&orow[lane], v, __ATOMIC_RELAXED, __HIP_MEMORY_SCOPE_AGENT);
        }
        if (t + 1 < T)
            poll_row16(Hout + (size_t)(out0 + t) * HD + lane * 16, h);
    }
}

// ---------------- fused 4-group scan ----------------
// grid = 1024 WGs x 64 threads (1 wave each), all resident (~1 wave/SIMD).
//   grp 0 (A): H1[t]   = tanh(Xa[t] + Wh1 @ H1[t-1])
//   grp 1 (C): Hp[t]   = tanh(Xc[t-1] + dWh @ Hp[t-1]), Hp[0]=dh0
//   grp 2 (D): U[t]    = b2 + Wx2 @ H1[t]                (feed-forward, lags A by 1)
//   grp 3 (B): Henc[t] = tanh(U[t] + Wh2 @ Henc[t-1])    (lags D by 1)
// Every group holds exactly ONE 4-row weight panel in VGPRs (64 regs) — the
// round-3-proven config; no branch needs >~110 VGPRs, so no spills.
__global__ __launch_bounds__(64) void scan_all(const float* __restrict__ Xa,
                                               const float* __restrict__ Wh1,
                                               const float* __restrict__ h01,
                                               float* __restrict__ H1,
                                               const float* __restrict__ Wx2,
                                               const float* __restrict__ Wh2,
                                               const float* __restrict__ b2,
                                               const float* __restrict__ h02,
                                               float* __restrict__ U,
                                               float* __restrict__ Henc,
                                               const float* __restrict__ Xc,
                                               const float* __restrict__ dWh,
                                               const float* __restrict__ dh0,
                                               float* __restrict__ Hp) {
    const int grp = blockIdx.x >> 8;
    const int wid = blockIdx.x & 255;
    const int lane = threadIdx.x;
    const int row0 = wid * 4;

    if (grp == 0) {
        scan_simple(Xa, Wh1, h01, H1, SEQ, 0, wid, lane);
    } else if (grp == 1) {
        scan_simple(Xc, dWh, dh0, Hp, SEQ - 1, 1, wid, lane);
    } else if (grp == 2) {
        // ---- D: U[t] = b2 + Wx2 @ H1[t] (blocking poll on H1[t]) ----
        float4 w[4][4];
#pragma unroll
        for (int r = 0; r < 4; ++r) {
            const float* wp = Wx2 + (size_t)(row0 + r) * HD + lane * 16;
#pragma unroll
            for (int c = 0; c < 4; ++c) w[r][c] = *(const float4*)(wp + c * 4);
        }
        float bv = (lane < 4) ? b2[row0 + lane] : 0.f;
        float hx[16];
        for (int t = 0; t < SEQ; ++t) {
            poll_row16(H1 + (size_t)t * HD + lane * 16, hx);
            float acc[4];
#pragma unroll
            for (int r = 0; r < 4; ++r) {
                float a = 0.f;
#pragma unroll
                for (int c = 0; c < 4; ++c) {
                    const float4 wv = w[r][c];
                    a += wv.x * hx[c * 4 + 0] + wv.y * hx[c * 4 + 1] +
                         wv.z * hx[c * 4 + 2] + wv.w * hx[c * 4 + 3];
                }
                acc[r] = a;
            }
#pragma unroll
            for (int r = 0; r < 4; ++r) {
#pragma unroll
                for (int off = 32; off; off >>= 1) acc[r] += __shfl_xor(acc[r], off);
            }
            if (lane < 4)
                __hip_atomic_store(&U[(size_t)t * HD + row0 + lane], bv + acc[lane],
                                   __ATOMIC_RELAXED, __HIP_MEMORY_SCOPE_AGENT);
        }
    } else {
        // ---- B: Henc[t] = tanh(U[t] + Wh2 @ Henc[t-1]) ----
        float4 w[4][4];
#pragma unroll
        for (int r = 0; r < 4; ++r) {
            const float* wp = Wh2 + (size_t)(row0 + r) * HD + lane * 16;
#pragma unroll
            for (int c = 0; c < 4; ++c) w[r][c] = *(const float4*)(wp + c * 4);
        }
        float hh[16];
#pragma unroll
        for (int c = 0; c < 16; ++c) hh[c] = h02[lane * 16 + c];
        // prologue: poll u[0] (lanes 0..3, 1 dword each)
        float uv = 0.f;
        {
            unsigned pend = (lane < 4) ? 1u : 0u;
            const float* up = U + row0 + lane;
            for (;;) {
                if (pend) {
                    float v = __hip_atomic_load(up, __ATOMIC_RELAXED, __HIP_MEMORY_SCOPE_AGENT);
                    uv = v;
                    if (__float_as_uint(v) != SENT) pend = 0;
                }
                if (__all(pend == 0)) break;
                __builtin_amdgcn_s_sleep(1);
            }
        }
        for (int t = 0; t < SEQ; ++t) {
            float acc[4];
#pragma unroll
            for (int r = 0; r < 4; ++r) {
                float a = 0.f;
#pragma unroll
                for (int c = 0; c < 4; ++c) {
                    const float4 wv = w[r][c];
                    a += wv.x * hh[c * 4 + 0] + wv.y * hh[c * 4 + 1] +
                         wv.z * hh[c * 4 + 2] + wv.w * hh[c * 4 + 3];
                }
                acc[r] = a;
            }
#pragma unroll
            for (int r = 0; r < 4; ++r) {
#pragma unroll
                for (int off = 32; off; off >>= 1) acc[r] += __shfl_xor(acc[r], off);
            }
            if (lane < 4) {
                float v = tanhf(uv + acc[lane]);
                __hip_atomic_store(&Henc[(size_t)t * HD + row0 + lane], v,
                                   __ATOMIC_RELAXED, __HIP_MEMORY_SCOPE_AGENT);
            }
            if (t + 1 < SEQ) {
                // merged poll: Henc[t] -> hh (16 dwords) AND u[t+1] -> uv (lanes<4)
                const float* hrow = Henc + (size_t)t * HD + lane * 16;
                const float* urow = U + (size_t)(t + 1) * HD + row0 + lane;
                unsigned pend = 0xFFFFu | ((lane < 4) ? 0x10000u : 0u);
                for (;;) {
#pragma unroll
                    for (int c = 0; c < 16; ++c) {
                        if (pend & (1u << c)) {
                            float v = __hip_atomic_load(&hrow[c], __ATOMIC_RELAXED, __HIP_MEMORY_SCOPE_AGENT);
                            hh[c] = v;
                            if (__float_as_uint(v) != SENT) pend &= ~(1u << c);
                        }
                    }
                    if (pend & 0x10000u) {
                        float v = __hip_atomic_load(urow, __ATOMIC_RELAXED, __HIP_MEMORY_SCOPE_AGENT);
                        uv = v;
                        if (__float_as_uint(v) != SENT) pend &= ~0x10000u;
                    }
                    if (__all(pend == 0)) break;
                    __builtin_amdgcn_s_sleep(1);
                }
            }
        }
    }
}

// ---------------- row softmax in place ----------------
__global__ __launch_bounds__(256) void softmax_rows(float* __restrict__ S, int N) {
    __shared__ float red[256];
    const int row = blockIdx.x, tid = threadIdx.x;
    float* r = S + (size_t)row * N;
    float lm = -INFINITY;
    for (int i = tid; i < N; i += 256) lm = fmaxf(lm, r[i]);
    red[tid] = lm; __syncthreads();
    for (int o = 128; o; o >>= 1) { if (tid < o) red[tid] = fmaxf(red[tid], red[tid + o]); __syncthreads(); }
    const float M = red[0]; __syncthreads();
    float ls = 0.f;
    for (int i = tid; i < N; i += 256) { float e = expf(r[i] - M); r[i] = e; ls += e; }
    red[tid] = ls; __syncthreads();
    for (int o = 128; o; o >>= 1) { if (tid < o) red[tid] += red[tid + o]; __syncthreads(); }
    const float inv = 1.f / red[0];
    for (int i = tid; i < N; i += 256) r[i] *= inv;
}

// ---------------- online logsumexp over a logits chunk ----------------
__global__ __launch_bounds__(256) void lse_chunk(const float* __restrict__ L, int CN, int c0,
                                                 const int* __restrict__ tgt, float* __restrict__ m,
                                                 float* __restrict__ s, float* __restrict__ tl) {
    __shared__ float red[256];
    const int row = blockIdx.x, tid = threadIdx.x;
    const float* lr = L + (size_t)row * CN;
    float lm = -INFINITY;
    for (int i = tid; i < CN; i += 256) lm = fmaxf(lm, lr[i]);
    red[tid] = lm; __syncthreads();
    for (int o = 128; o; o >>= 1) { if (tid < o) red[tid] = fmaxf(red[tid], red[tid + o]); __syncthreads(); }
    const float M = red[0]; __syncthreads();
    float ls = 0.f;
    for (int i = tid; i < CN; i += 256) ls += expf(lr[i] - M);
    red[tid] = ls; __syncthreads();
    for (int o = 128; o; o >>= 1) { if (tid < o) red[tid] += red[tid + o]; __syncthreads(); }
    if (tid == 0) {
        const float S = red[0];
        const float m0 = m[row];
        const float nm = fmaxf(m0, M);
        const float s0 = s[row];
        const float ns = (m0 == -INFINITY ? 0.f : s0 * expf(m0 - nm)) + S * expf(M - nm);
        m[row] = nm; s[row] = ns;
        const int tg = tgt[row] - c0;
        if (tg >= 0 && tg < CN) tl[row] = lr[tg];
    }
}

// ---------------- final: sum_t (m + log s - tgt_logit) ----------------
__global__ __launch_bounds__(512) void final_loss(const float* __restrict__ m, const float* __restrict__ s,
                                                  const float* __restrict__ tl, float* __restrict__ out) {
    __shared__ float red[512];
    const int tid = threadIdx.x;
    red[tid] = m[tid] + logf(s[tid]) - tl[tid];
    __syncthreads();
    for (int o = 256; o; o >>= 1) { if (tid < o) red[tid] += red[tid + o]; __syncthreads(); }
    if (tid == 0) out[0] = red[0];
}

extern "C" void kernel_launch(void* const* d_in, const int* in_sizes, int n_in,
                              void* d_out, int out_size, void* d_ws, size_t ws_size,
                              hipStream_t stream) {
    const int* src_nums  = (const int*)d_in[0];
    const int* tgt_nums  = (const int*)d_in[1];
    const float* src_emb = (const float*)d_in[2];
    const float* Wx1     = (const float*)d_in[3];
    const float* Wh1     = (const float*)d_in[4];
    const float* b1      = (const float*)d_in[5];
    const float* h01     = (const float*)d_in[6];
    const float* Wx2     = (const float*)d_in[7];
    const float* Wh2     = (const float*)d_in[8];
    const float* b2      = (const float*)d_in[9];
    const float* h02     = (const float*)d_in[10];
    const float* tgt_emb = (const float*)d_in[11];
    const float* dh0     = (const float*)d_in[12];
    const float* dWx     = (const float*)d_in[13];
    const float* dWh     = (const float*)d_in[14];
    const float* db      = (const float*)d_in[15];
    const float* tnhW    = (const float*)d_in[16];
    const float* tnhb    = (const float*)d_in[17];
    const float* outW    = (const float*)d_in[18];
    const float* outb    = (const float*)d_in[19];
    float* out = (float*)d_out;

    float* ws = (float*)d_ws;
    size_t off = 0;
    auto alloc = [&](size_t n) { float* p = ws + off; off += n; return p; };
    float* E     = alloc((size_t)SEQ * HD);
    float* Xa    = alloc((size_t)SEQ * HD);
    float* Xc    = alloc((size_t)SEQ * HD);
    float* H1    = alloc((size_t)SEQ * HD);   // H1, Henc, Hp, U contiguous: one sentinel fill
    float* Henc  = alloc((size_t)SEQ * HD);
    float* Hp    = alloc((size_t)SEQ * HD);
    float* U     = alloc((size_t)SEQ * HD);
    float* HencT = alloc((size_t)HD * SEQ);
    float* Satt  = alloc((size_t)SEQ * SEQ);
    float* CH    = alloc((size_t)SEQ * 2 * HD);
    float* Z     = alloc((size_t)SEQ * HD);
    float* Lc    = alloc((size_t)SEQ * NCHUNK);
    float* mrow  = alloc(SEQ);
    float* srow  = alloc(SEQ);
    float* tlrow = alloc(SEQ);

    init_state<<<1, 512, 0, stream>>>(mrow, srow, tlrow);
    fill_sentinel<<<1024, 256, 0, stream>>>((float4*)H1, 4 * SEQ * HD / 4);

    // ---- precompute scan inputs (E reused sequentially; stream-ordered) ----
    gather_rows<<<SEQ, 256, 0, stream>>>(src_emb, src_nums, E, HD);
    gemm_nt<<<dim3(HD / 64, SEQ / 64), 256, 0, stream>>>(E, Wx1, b1, Xa, SEQ, HD, HD, HD, 0);
    gather_rows<<<SEQ, 256, 0, stream>>>(tgt_emb, tgt_nums, E, HD);
    gemm_nt<<<dim3(HD / 64, SEQ / 64), 256, 0, stream>>>(E, dWx, db, Xc, SEQ, HD, HD, HD, 0);

    // ---- all recurrence chains, concurrent + pipelined (A, C, D, B) ----
    scan_all<<<4 * SCAN_WGS, 64, 0, stream>>>(Xa, Wh1, h01, H1,
                                              Wx2, Wh2, b2, h02, U, Henc,
                                              Xc, dWh, dh0, Hp);

    // ---- batched attention ----
    gemm_nt<<<dim3(SEQ / 64, SEQ / 64), 256, 0, stream>>>(Hp, Henc, nullptr, Satt, SEQ, SEQ, HD, SEQ, 0);
    softmax_rows<<<SEQ, 256, 0, stream>>>(Satt, SEQ);
    transpose_k<<<dim3(HD / 32, SEQ / 32), dim3(32, 8), 0, stream>>>(Henc, HencT, SEQ, HD);
    gemm_nt<<<dim3(HD / 64, SEQ / 64), 256, 0, stream>>>(Satt, HencT, nullptr, CH, SEQ, HD, SEQ, 2 * HD, 0);
    copy_right<<<SEQ, 256, 0, stream>>>(Hp, CH);
    gemm_nt<<<dim3(HD / 64, SEQ / 64), 256, 0, stream>>>(CH, tnhW, tnhb, Z, SEQ, HD, 2 * HD, HD, 1);

    // ---- logits + online logsumexp, chunked over vocab ----
    for (int c = 0; c < VOCAB / NCHUNK; ++c) {
        gemm_nt<<<dim3(NCHUNK / 64, SEQ / 64), 256, 0, stream>>>(
            Z, outW + (size_t)c * NCHUNK * HD, outb + (size_t)c * NCHUNK, Lc, SEQ, NCHUNK, HD, NCHUNK, 0);
        lse_chunk<<<SEQ, 256, 0, stream>>>(Lc, NCHUNK, c * NCHUNK, tgt_nums, mrow, srow, tlrow);
    }
    final_loss<<<1, 512, 0, stream>>>(mrow, srow, tlrow, out);
}

// Round 8
// 3835.203 us; speedup vs baseline: 2.3875x; 1.3325x over previous
//
#include <hip/hip_runtime.h>
#include <math.h>

#define HD 1024
#define SEQ 512
#define VOCAB 32000
#define NCHUNK 8000
#define CHAIN_WGS 64    // per chain; 4 chains = 256 WGs x 256 thr = 1 WG/CU
#define SENT 0xAAAAAAAAu

// ---------------- init: LSE state + scan flags ----------------
__global__ __launch_bounds__(512) void init_state(float* m, float* s, float* tl, unsigned* flags) {
    int tid = threadIdx.x;
    m[tid] = -INFINITY;
    s[tid] = 0.f;
    tl[tid] = 0.f;
    if (tid < 3 * CHAIN_WGS) flags[tid] = 0u;
}

// ---------------- sentinel fill for scan output buffers ----------------
__global__ __launch_bounds__(256) void fill_sentinel(float4* p, int n4) {
    const float s = __uint_as_float(SENT);
    const float4 v = {s, s, s, s};
    int i = blockIdx.x * 256 + threadIdx.x;
    int stride = gridDim.x * 256;
    for (; i < n4; i += stride) p[i] = v;
}

// ---------------- embedding gather ----------------
__global__ __launch_bounds__(256) void gather_rows(const float* __restrict__ emb,
                                                   const int* __restrict__ idx,
                                                   float* __restrict__ out, int ncols) {
    int t = blockIdx.x;
    int src = idx[t];
    const float4* sp = (const float4*)(emb + (size_t)src * ncols);
    float4* dp = (float4*)(out + (size_t)t * ncols);
    for (int i = threadIdx.x; i < ncols / 4; i += blockDim.x) dp[i] = sp[i];
}

// ---------------- copy Hp into right half of CH ----------------
__global__ __launch_bounds__(256) void copy_right(const float* __restrict__ Hp, float* __restrict__ CH) {
    int t = blockIdx.x;
    const float4* sp = (const float4*)(Hp + (size_t)t * HD);
    float4* dp = (float4*)(CH + (size_t)t * (2 * HD) + HD);
    for (int i = threadIdx.x; i < HD / 4; i += blockDim.x) dp[i] = sp[i];
}

// ---------------- transpose ----------------
__global__ __launch_bounds__(256) void transpose_k(const float* __restrict__ in, float* __restrict__ out,
                                                   int R, int C) {
    __shared__ float tile[32][33];
    int c0 = blockIdx.x * 32, r0 = blockIdx.y * 32;
    int tx = threadIdx.x, ty = threadIdx.y;  // block (32,8)
    for (int i = ty; i < 32; i += 8)
        tile[i][tx] = in[(size_t)(r0 + i) * C + c0 + tx];
    __syncthreads();
    for (int i = ty; i < 32; i += 8)
        out[(size_t)(c0 + i) * R + r0 + tx] = tile[tx][i];
}

// ---------------- fp32 GEMM: C[M,N] = act(A[M,K] @ B[N,K]^T + bias[N]) ----------------
__global__ __launch_bounds__(256) void gemm_nt(const float* __restrict__ A, const float* __restrict__ B,
                                               const float* __restrict__ bias, float* __restrict__ C,
                                               int M, int N, int K, int ldc, int act) {
    __shared__ float As[16][68];
    __shared__ float Bs[16][68];
    const int tid = threadIdx.x;
    const int row0 = blockIdx.y * 64, col0 = blockIdx.x * 64;
    const int tx = tid & 15, ty = tid >> 4;
    const int lr = tid >> 2, lk = (tid & 3) << 2;
    const float* Ap = A + (size_t)(row0 + lr) * K + lk;
    const float* Bp = B + (size_t)(col0 + lr) * K + lk;
    float acc[4][4] = {};
    for (int k0 = 0; k0 < K; k0 += 16) {
        float4 a = *(const float4*)(Ap + k0);
        float4 b = *(const float4*)(Bp + k0);
        As[lk + 0][lr] = a.x; As[lk + 1][lr] = a.y; As[lk + 2][lr] = a.z; As[lk + 3][lr] = a.w;
        Bs[lk + 0][lr] = b.x; Bs[lk + 1][lr] = b.y; Bs[lk + 2][lr] = b.z; Bs[lk + 3][lr] = b.w;
        __syncthreads();
#pragma unroll
        for (int kk = 0; kk < 16; ++kk) {
            const float4 av = *(const float4*)&As[kk][ty * 4];
            const float4 bv = *(const float4*)&Bs[kk][tx * 4];
            const float a0[4] = {av.x, av.y, av.z, av.w};
            const float b0[4] = {bv.x, bv.y, bv.z, bv.w};
#pragma unroll
            for (int i = 0; i < 4; ++i)
#pragma unroll
                for (int j = 0; j < 4; ++j) acc[i][j] += a0[i] * b0[j];
        }
        __syncthreads();
    }
#pragma unroll
    for (int i = 0; i < 4; ++i) {
        float4 v;
        float* vp = &v.x;
#pragma unroll
        for (int j = 0; j < 4; ++j) {
            float x = acc[i][j];
            if (bias) x += bias[col0 + tx * 4 + j];
            if (act) x = tanhf(x);
            vp[j] = x;
        }
        *(float4*)(C + (size_t)(row0 + ty * 4 + i) * ldc + col0 + tx * 4) = v;
    }
}

// ================= scan building blocks =================
// 4 waves/WG; WG owns rows [16wid,16wid+16); wave w rows rowbase..rowbase+4;
// lane l holds W[row][16l..16l+16) in VGPRs (64 regs).  Sync protocol:
// producers store h (relaxed agent) then per-WG flag; consumers poll the 64
// FLAGS only (wave 0, 1 dword/lane), then ONE coalesced 4KB read of the row
// (sentinel-verified: covers flag-before-data visibility races) into
// XOR-swizzled LDS, then lanes pick up their 16 values.

__device__ __forceinline__ int swz4(int j) { return j ^ ((j >> 3) & 7); }  // f4-index swizzle

__device__ __forceinline__ void wait_flags(const unsigned* f, unsigned want, int tid) {
    if (tid < 64) {
        for (;;) {
            unsigned v = __hip_atomic_load(&f[tid], __ATOMIC_RELAXED, __HIP_MEMORY_SCOPE_AGENT);
            if (__all(v >= want)) break;
            __builtin_amdgcn_s_sleep(1);
        }
    }
    __syncthreads();
}

__device__ __forceinline__ void row_to_regs(const float* __restrict__ row, float* hlds,
                                            float* h, int tid, int lane) {
    // one float4 per thread, coalesced; verify each dword against SENT
    const float* p = row + 4 * tid;
    float4 v;
    float* vp = &v.x;
    unsigned pend = 0xFu;
    for (;;) {
#pragma unroll
        for (int c = 0; c < 4; ++c) {
            if (pend & (1u << c)) {
                float x = __hip_atomic_load(&p[c], __ATOMIC_RELAXED, __HIP_MEMORY_SCOPE_AGENT);
                vp[c] = x;
                if (__float_as_uint(x) != SENT) pend &= ~(1u << c);
            }
        }
        if (__all(pend == 0)) break;
        __builtin_amdgcn_s_sleep(1);
    }
    ((float4*)hlds)[swz4(tid)] = v;
    __syncthreads();
#pragma unroll
    for (int r = 0; r < 4; ++r) {
        float4 hv = ((float4*)hlds)[swz4(4 * lane + r)];
        h[4 * r + 0] = hv.x; h[4 * r + 1] = hv.y; h[4 * r + 2] = hv.z; h[4 * r + 3] = hv.w;
    }
}

__device__ __forceinline__ float poll1(const float* p) {
    for (;;) {
        float v = __hip_atomic_load(p, __ATOMIC_RELAXED, __HIP_MEMORY_SCOPE_AGENT);
        if (__float_as_uint(v) != SENT) return v;
        __builtin_amdgcn_s_sleep(1);
    }
}

__device__ __forceinline__ void mac16(const float4 (&w)[4][4], const float* h, float* acc) {
#pragma unroll
    for (int r = 0; r < 4; ++r) {
        float a = 0.f;
#pragma unroll
        for (int c = 0; c < 4; ++c) {
            const float4 wv = w[r][c];
            a += wv.x * h[c * 4 + 0] + wv.y * h[c * 4 + 1] +
                 wv.z * h[c * 4 + 2] + wv.w * h[c * 4 + 3];
        }
        acc[r] += a;
    }
}

__device__ __forceinline__ void butterfly4(float* acc) {
#pragma unroll
    for (int r = 0; r < 4; ++r) {
#pragma unroll
        for (int off = 32; off; off >>= 1) acc[r] += __shfl_xor(acc[r], off);
    }
}

// self-recurrent chain (A and C): h_t = tanh(X[t] + Wh @ h_{t-1})
__device__ __forceinline__ void scan_rec(const float* __restrict__ X, const float* __restrict__ Wh,
                                         const float* __restrict__ h0, float* __restrict__ Hout,
                                         unsigned* __restrict__ flags, int T, int write_h0,
                                         float* hlds, int tid, int lane, int rowbase, int wid) {
    float4 w[4][4];
#pragma unroll
    for (int r = 0; r < 4; ++r)
#pragma unroll
        for (int c = 0; c < 4; ++c)
            w[r][c] = *(const float4*)(Wh + (size_t)(rowbase + r) * HD + lane * 16 + c * 4);
    const int out0 = write_h0 ? 1 : 0;
    if (write_h0 && lane < 4) Hout[rowbase + lane] = h0[rowbase + lane];
    float h[16];
#pragma unroll
    for (int c = 0; c < 16; ++c) h[c] = h0[lane * 16 + c];

    for (int t = 0; t < T; ++t) {
        float xv = 0.f;
        if (lane < 4) xv = X[(size_t)t * HD + rowbase + lane];
        float acc[4] = {};
        mac16(w, h, acc);
        butterfly4(acc);
        if (lane < 4)
            __hip_atomic_store(&Hout[(size_t)(out0 + t) * HD + rowbase + lane],
                               tanhf(xv + acc[lane]), __ATOMIC_RELAXED, __HIP_MEMORY_SCOPE_AGENT);
        __syncthreads();
        if (tid == 0)
            __hip_atomic_store(&flags[wid], (unsigned)(t + 1), __ATOMIC_RELAXED, __HIP_MEMORY_SCOPE_AGENT);
        if (t + 1 < T) {
            wait_flags(flags, (unsigned)(t + 1), tid);
            row_to_regs(Hout + (size_t)(out0 + t) * HD, hlds, h, tid, lane);
        }
    }
}

// ---------------- fused 4-group scan ----------------
// grid = 256 WGs x 256 threads (1 WG/CU).
//   grp 0 (A): H1[t]   = tanh(Xa[t] + Wh1 @ H1[t-1])            [flags fA]
//   grp 1 (C): Hp[t]   = tanh(Xc[t-1] + dWh @ Hp[t-1]), Hp[0]=dh0 [flags fC]
//   grp 2 (D): U[t]    = b2 + Wx2 @ H1[t]    (consumes fA; no flag of its own)
//   grp 3 (B): Henc[t] = tanh(U[t] + Wh2 @ Henc[t-1])           [flags fB; U narrow-polled]
__global__ __launch_bounds__(256) void scan_all(const float* __restrict__ Xa,
                                                const float* __restrict__ Wh1,
                                                const float* __restrict__ h01,
                                                float* __restrict__ H1,
                                                const float* __restrict__ Wx2,
                                                const float* __restrict__ Wh2,
                                                const float* __restrict__ b2,
                                                const float* __restrict__ h02,
                                                float* __restrict__ U,
                                                float* __restrict__ Henc,
                                                const float* __restrict__ Xc,
                                                const float* __restrict__ dWh,
                                                const float* __restrict__ dh0,
                                                float* __restrict__ Hp,
                                                unsigned* __restrict__ fA,
                                                unsigned* __restrict__ fC,
                                                unsigned* __restrict__ fB) {
    __shared__ float hlds[HD];
    const int grp = blockIdx.x >> 6;
    const int wid = blockIdx.x & 63;
    const int tid = threadIdx.x;
    const int wave = tid >> 6, lane = tid & 63;
    const int rowbase = wid * 16 + wave * 4;

    if (grp == 0) {
        scan_rec(Xa, Wh1, h01, H1, fA, SEQ, 0, hlds, tid, lane, rowbase, wid);
    } else if (grp == 1) {
        scan_rec(Xc, dWh, dh0, Hp, fC, SEQ - 1, 1, hlds, tid, lane, rowbase, wid);
    } else if (grp == 2) {
        // D: feed-forward off A
        float4 w[4][4];
#pragma unroll
        for (int r = 0; r < 4; ++r)
#pragma unroll
            for (int c = 0; c < 4; ++c)
                w[r][c] = *(const float4*)(Wx2 + (size_t)(rowbase + r) * HD + lane * 16 + c * 4);
        float bv = (lane < 4) ? b2[rowbase + lane] : 0.f;
        float hx[16];
        for (int t = 0; t < SEQ; ++t) {
            wait_flags(fA, (unsigned)(t + 1), tid);
            row_to_regs(H1 + (size_t)t * HD, hlds, hx, tid, lane);
            float acc[4] = {};
            mac16(w, hx, acc);
            butterfly4(acc);
            if (lane < 4)
                __hip_atomic_store(&U[(size_t)t * HD + rowbase + lane], bv + acc[lane],
                                   __ATOMIC_RELAXED, __HIP_MEMORY_SCOPE_AGENT);
        }
    } else {
        // B: self-recurrent with precomputed input U
        float4 w[4][4];
#pragma unroll
        for (int r = 0; r < 4; ++r)
#pragma unroll
            for (int c = 0; c < 4; ++c)
                w[r][c] = *(const float4*)(Wh2 + (size_t)(rowbase + r) * HD + lane * 16 + c * 4);
        float hh[16];
#pragma unroll
        for (int c = 0; c < 16; ++c) hh[c] = h02[lane * 16 + c];
        float uv = 0.f;
        if (lane < 4) uv = poll1(U + rowbase + lane);
        for (int t = 0; t < SEQ; ++t) {
            float acc[4] = {};
            mac16(w, hh, acc);
            butterfly4(acc);
            if (lane < 4)
                __hip_atomic_store(&Henc[(size_t)t * HD + rowbase + lane], tanhf(uv + acc[lane]),
                                   __ATOMIC_RELAXED, __HIP_MEMORY_SCOPE_AGENT);
            __syncthreads();
            if (tid == 0)
                __hip_atomic_store(&fB[wid], (unsigned)(t + 1), __ATOMIC_RELAXED, __HIP_MEMORY_SCOPE_AGENT);
            if (t + 1 < SEQ) {
                wait_flags(fB, (unsigned)(t + 1), tid);
                row_to_regs(Henc + (size_t)t * HD, hlds, hh, tid, lane);
                if (lane < 4) uv = poll1(U + (size_t)(t + 1) * HD + rowbase + lane);
            }
        }
    }
}

// ---------------- row softmax in place ----------------
__global__ __launch_bounds__(256) void softmax_rows(float* __restrict__ S, int N) {
    __shared__ float red[256];
    const int row = blockIdx.x, tid = threadIdx.x;
    float* r = S + (size_t)row * N;
    float lm = -INFINITY;
    for (int i = tid; i < N; i += 256) lm = fmaxf(lm, r[i]);
    red[tid] = lm; __syncthreads();
    for (int o = 128; o; o >>= 1) { if (tid < o) red[tid] = fmaxf(red[tid], red[tid + o]); __syncthreads(); }
    const float M = red[0]; __syncthreads();
    float ls = 0.f;
    for (int i = tid; i < N; i += 256) { float e = expf(r[i] - M); r[i] = e; ls += e; }
    red[tid] = ls; __syncthreads();
    for (int o = 128; o; o >>= 1) { if (tid < o) red[tid] += red[tid + o]; __syncthreads(); }
    const float inv = 1.f / red[0];
    for (int i = tid; i < N; i += 256) r[i] *= inv;
}

// ---------------- online logsumexp over a logits chunk ----------------
__global__ __launch_bounds__(256) void lse_chunk(const float* __restrict__ L, int CN, int c0,
                                                 const int* __restrict__ tgt, float* __restrict__ m,
                                                 float* __restrict__ s, float* __restrict__ tl) {
    __shared__ float red[256];
    const int row = blockIdx.x, tid = threadIdx.x;
    const float* lr = L + (size_t)row * CN;
    float lm = -INFINITY;
    for (int i = tid; i < CN; i += 256) lm = fmaxf(lm, lr[i]);
    red[tid] = lm; __syncthreads();
    for (int o = 128; o; o >>= 1) { if (tid < o) red[tid] = fmaxf(red[tid], red[tid + o]); __syncthreads(); }
    const float M = red[0]; __syncthreads();
    float ls = 0.f;
    for (int i = tid; i < CN; i += 256) ls += expf(lr[i] - M);
    red[tid] = ls; __syncthreads();
    for (int o = 128; o; o >>= 1) { if (tid < o) red[tid] += red[tid + o]; __syncthreads(); }
    if (tid == 0) {
        const float S = red[0];
        const float m0 = m[row];
        const float nm = fmaxf(m0, M);
        const float s0 = s[row];
        const float ns = (m0 == -INFINITY ? 0.f : s0 * expf(m0 - nm)) + S * expf(M - nm);
        m[row] = nm; s[row] = ns;
        const int tg = tgt[row] - c0;
        if (tg >= 0 && tg < CN) tl[row] = lr[tg];
    }
}

// ---------------- final loss ----------------
__global__ __launch_bounds__(512) void final_loss(const float* __restrict__ m, const float* __restrict__ s,
                                                  const float* __restrict__ tl, float* __restrict__ out) {
    __shared__ float red[512];
    const int tid = threadIdx.x;
    red[tid] = m[tid] + logf(s[tid]) - tl[tid];
    __syncthreads();
    for (int o = 256; o; o >>= 1) { if (tid < o) red[tid] += red[tid + o]; __syncthreads(); }
    if (tid == 0) out[0] = red[0];
}

extern "C" void kernel_launch(void* const* d_in, const int* in_sizes, int n_in,
                              void* d_out, int out_size, void* d_ws, size_t ws_size,
                              hipStream_t stream) {
    const int* src_nums  = (const int*)d_in[0];
    const int* tgt_nums  = (const int*)d_in[1];
    const float* src_emb = (const float*)d_in[2];
    const float* Wx1     = (const float*)d_in[3];
    const float* Wh1     = (const float*)d_in[4];
    const float* b1      = (const float*)d_in[5];
    const float* h01     = (const float*)d_in[6];
    const float* Wx2     = (const float*)d_in[7];
    const float* Wh2     = (const float*)d_in[8];
    const float* b2      = (const float*)d_in[9];
    const float* h02     = (const float*)d_in[10];
    const float* tgt_emb = (const float*)d_in[11];
    const float* dh0     = (const float*)d_in[12];
    const float* dWx     = (const float*)d_in[13];
    const float* dWh     = (const float*)d_in[14];
    const float* db      = (const float*)d_in[15];
    const float* tnhW    = (const float*)d_in[16];
    const float* tnhb    = (const float*)d_in[17];
    const float* outW    = (const float*)d_in[18];
    const float* outb    = (const float*)d_in[19];
    float* out = (float*)d_out;

    float* ws = (float*)d_ws;
    size_t off = 0;
    auto alloc = [&](size_t n) { float* p = ws + off; off += n; return p; };
    float* E     = alloc((size_t)SEQ * HD);
    float* Xa    = alloc((size_t)SEQ * HD);
    float* Xc    = alloc((size_t)SEQ * HD);
    float* H1    = alloc((size_t)SEQ * HD);   // H1, Henc, Hp, U contiguous: one sentinel fill
    float* Henc  = alloc((size_t)SEQ * HD);
    float* Hp    = alloc((size_t)SEQ * HD);
    float* U     = alloc((size_t)SEQ * HD);
    float* HencT = alloc((size_t)HD * SEQ);
    float* Satt  = alloc((size_t)SEQ * SEQ);
    float* CH    = alloc((size_t)SEQ * 2 * HD);
    float* Z     = alloc((size_t)SEQ * HD);
    float* Lc    = alloc((size_t)SEQ * NCHUNK);
    float* mrow  = alloc(SEQ);
    float* srow  = alloc(SEQ);
    float* tlrow = alloc(SEQ);
    unsigned* flags = (unsigned*)(ws + off); off += 3 * CHAIN_WGS;
    unsigned* fA = flags;
    unsigned* fC = flags + CHAIN_WGS;
    unsigned* fB = flags + 2 * CHAIN_WGS;

    init_state<<<1, 512, 0, stream>>>(mrow, srow, tlrow, flags);
    fill_sentinel<<<1024, 256, 0, stream>>>((float4*)H1, 4 * SEQ * HD / 4);

    // ---- precompute scan inputs ----
    gather_rows<<<SEQ, 256, 0, stream>>>(src_emb, src_nums, E, HD);
    gemm_nt<<<dim3(HD / 64, SEQ / 64), 256, 0, stream>>>(E, Wx1, b1, Xa, SEQ, HD, HD, HD, 0);
    gather_rows<<<SEQ, 256, 0, stream>>>(tgt_emb, tgt_nums, E, HD);
    gemm_nt<<<dim3(HD / 64, SEQ / 64), 256, 0, stream>>>(E, dWx, db, Xc, SEQ, HD, HD, HD, 0);

    // ---- all recurrence chains, concurrent + pipelined (A, C, D, B) ----
    scan_all<<<4 * CHAIN_WGS, 256, 0, stream>>>(Xa, Wh1, h01, H1,
                                                Wx2, Wh2, b2, h02, U, Henc,
                                                Xc, dWh, dh0, Hp, fA, fC, fB);

    // ---- batched attention ----
    gemm_nt<<<dim3(SEQ / 64, SEQ / 64), 256, 0, stream>>>(Hp, Henc, nullptr, Satt, SEQ, SEQ, HD, SEQ, 0);
    softmax_rows<<<SEQ, 256, 0, stream>>>(Satt, SEQ);
    transpose_k<<<dim3(HD / 32, SEQ / 32), dim3(32, 8), 0, stream>>>(Henc, HencT, SEQ, HD);
    gemm_nt<<<dim3(HD / 64, SEQ / 64), 256, 0, stream>>>(Satt, HencT, nullptr, CH, SEQ, HD, SEQ, 2 * HD, 0);
    copy_right<<<SEQ, 256, 0, stream>>>(Hp, CH);
    gemm_nt<<<dim3(HD / 64, SEQ / 64), 256, 0, stream>>>(CH, tnhW, tnhb, Z, SEQ, HD, 2 * HD, HD, 1);

    // ---- logits + online logsumexp, chunked over vocab ----
    for (int c = 0; c < VOCAB / NCHUNK; ++c) {
        gemm_nt<<<dim3(NCHUNK / 64, SEQ / 64), 256, 0, stream>>>(
            Z, outW + (size_t)c * NCHUNK * HD, outb + (size_t)c * NCHUNK, Lc, SEQ, NCHUNK, HD, NCHUNK, 0);
        lse_chunk<<<SEQ, 256, 0, stream>>>(Lc, NCHUNK, c * NCHUNK, tgt_nums, mrow, srow, tlrow);
    }
    final_loss<<<1, 512, 0, stream>>>(mrow, srow, tlrow, out);
}